// Round 5
// baseline (360.607 us; speedup 1.0000x reference)
//
#include <hip/hip_runtime.h>
#include <math.h>

constexpr int NB = 64;
constexpr int NS = 1024;
constexpr int NH = 1024;
constexpr int NE = 1024;
constexpr int NV = 50257;
constexpr int NK2 = 2048;

typedef __bf16 bf16_8 __attribute__((ext_vector_type(8)));
typedef float  f32x4  __attribute__((ext_vector_type(4)));

// ---------------- build A_g = [emb[x] | h] (64 x 2048) in bf16
__global__ __launch_bounds__(256) void k_cvtAg(const int* __restrict__ x,
    const float* __restrict__ h, const float* __restrict__ emb,
    __bf16* __restrict__ Ag) {
  int t = blockIdx.x * 256 + threadIdx.x;  // 0..131071
  int b = t >> 11, k = t & 2047;
  float v = (k < NE) ? emb[(size_t)x[b] * NE + k] : h[b * NH + (k - NE)];
  Ag[t] = (__bf16)v;
}

// ---------------- gates GEMM via bf16 MFMA (W streamed, no LDS staging)
__global__ __launch_bounds__(256) void k_gates_mfma(const __bf16* __restrict__ Ag,
    const float* __restrict__ Wih, const float* __restrict__ bih,
    const float* __restrict__ Whh, const float* __restrict__ bhh,
    float* __restrict__ gates) {
  __shared__ f32x4 red[4][4][64];
  int lane = threadIdx.x & 63;
  int wave = threadIdx.x >> 6;
  int col  = lane & 15;
  int grp  = lane >> 4;
  int j    = blockIdx.x * 16 + col;

  const float* Wsel = (wave < 2) ? Wih : Whh;
  const float*  wp  = Wsel + (size_t)j * 1024 + (wave & 1) * 512 + grp * 8;
  const __bf16* ap  = Ag + wave * 512 + grp * 8;

  f32x4 acc[4] = {};
#pragma unroll 4
  for (int ks = 0; ks < 16; ++ks) {
    int kb = ks * 32;
    float4 b0 = *(const float4*)(wp + kb);
    float4 b1 = *(const float4*)(wp + kb + 4);
    bf16_8 bf;
    bf[0] = (__bf16)b0.x; bf[1] = (__bf16)b0.y;
    bf[2] = (__bf16)b0.z; bf[3] = (__bf16)b0.w;
    bf[4] = (__bf16)b1.x; bf[5] = (__bf16)b1.y;
    bf[6] = (__bf16)b1.z; bf[7] = (__bf16)b1.w;
#pragma unroll
    for (int m = 0; m < 4; ++m) {
      bf16_8 a = *(const bf16_8*)(ap + (m * 16 + col) * NK2 + kb);
      acc[m] = __builtin_amdgcn_mfma_f32_16x16x32_bf16(a, bf, acc[m], 0, 0, 0);
    }
  }
#pragma unroll
  for (int m = 0; m < 4; ++m) red[wave][m][lane] = acc[m];
  __syncthreads();
  f32x4 s = red[0][wave][lane];
#pragma unroll
  for (int wv = 1; wv < 4; ++wv) s += red[wv][wave][lane];
  float bias = bih[j] + bhh[j];
  int b = wave * 16 + grp * 4;
#pragma unroll
  for (int r = 0; r < 4; ++r)
    gates[(b + r) * 4096 + j] = s[r] + bias;
}

// ---------------- LSTM cell elementwise (also emits bf16 h_new into A[:,1024:])
__global__ __launch_bounds__(256) void k_lstm(const float* __restrict__ gates,
    const float* __restrict__ c, float* __restrict__ hc_out,
    __bf16* __restrict__ A_bf) {
  int t = blockIdx.x * 256 + threadIdx.x;  // 0..NB*NH
  int b = t >> 10, hh = t & 1023;
  float ig = gates[b * 4096 + hh];
  float fg = gates[b * 4096 + 1024 + hh];
  float gg = gates[b * 4096 + 2048 + hh];
  float og = gates[b * 4096 + 3072 + hh];
  float i_ = 1.f / (1.f + expf(-ig));
  float f_ = 1.f / (1.f + expf(-fg));
  float g_ = tanhf(gg);
  float o_ = 1.f / (1.f + expf(-og));
  float cn = f_ * c[t] + i_ * g_;
  float hn = o_ * tanhf(cn);
  hc_out[t] = hn;                 // h_new
  hc_out[NB * NH + t] = cn;       // c_new
  A_bf[b * NK2 + 1024 + hh] = (__bf16)hn;
}

// ---------------- t = h_new @ W_bilin
__global__ __launch_bounds__(256) void k_bilin(const float* __restrict__ hnew,
    const float* __restrict__ Wb, float* __restrict__ t_out) {
  int b = blockIdx.x >> 2;
  int k = ((blockIdx.x & 3) << 8) + threadIdx.x;
  const float* hb = hnew + b * NH;
  float acc = 0.f;
#pragma unroll 8
  for (int hh = 0; hh < NH; ++hh)
    acc += hb[hh] * Wb[hh * NH + k];
  t_out[b * NH + k] = acc;
}

// ---------------- fused flash attention: energy + online softmax + context partial
// One block per (b, 64-row chunk). Streams enc ONCE: 8-row sub-chunks through LDS.
// Masked rows (s>=len) get value 0 (not -inf) and DO accumulate, per reference.
__global__ __launch_bounds__(256) void k_attn(const float* __restrict__ t_in,
    const float* __restrict__ enc, const int* __restrict__ length,
    float* __restrict__ ctxp, float* __restrict__ ml) {
  __shared__ float enc_lds[8 * 1024];
  __shared__ float e_lds[8];
  int b  = blockIdx.x >> 4;
  int ch = blockIdx.x & 15;
  int s0 = ch * 64;
  int tid = threadIdx.x;
  int lane = tid & 63;
  int wave = tid >> 6;
  int len = length[b];

  // per-lane slice of t[b] (reused for all rows)
  const float4* tp4 = (const float4*)(t_in + b * NH);
  float4 tv[4];
#pragma unroll
  for (int i = 0; i < 4; ++i) tv[i] = tp4[i * 64 + lane];

  const float4* ep4 = (const float4*)(enc + ((size_t)b * NS + s0) * NH);

  float4 R[8];
#pragma unroll
  for (int p = 0; p < 8; ++p) R[p] = ep4[p * 256 + tid];

  float m_run = -1e30f, l_run = 0.f;
  f32x4 acc = {0.f, 0.f, 0.f, 0.f};

  for (int sc = 0; sc < 8; ++sc) {
    // stage sub-chunk into LDS
#pragma unroll
    for (int p = 0; p < 8; ++p)
      *(float4*)(enc_lds + p * 1024 + tid * 4) = R[p];
    // prefetch next sub-chunk
    if (sc < 7) {
#pragma unroll
      for (int p = 0; p < 8; ++p) R[p] = ep4[(sc + 1) * 2048 + p * 256 + tid];
    }
    __syncthreads();

    // energy: 4 waves x 2 rows, lane-parallel dot from LDS
#pragma unroll
    for (int r = 0; r < 2; ++r) {
      int s_loc = wave * 2 + r;
      float a = 0.f;
#pragma unroll
      for (int i = 0; i < 4; ++i) {
        float4 e = *(const float4*)(enc_lds + s_loc * 1024 + i * 256 + lane * 4);
        a += tv[i].x * e.x + tv[i].y * e.y + tv[i].z * e.z + tv[i].w * e.w;
      }
#pragma unroll
      for (int off = 32; off; off >>= 1) a += __shfl_xor(a, off);
      if (lane == 0) e_lds[s_loc] = a;
    }
    __syncthreads();

    // online softmax update (redundant per-thread, identical results)
    float v[8];
#pragma unroll
    for (int s = 0; s < 8; ++s) {
      int sg = s0 + sc * 8 + s;
      v[s] = (sg < len) ? e_lds[s] : 0.f;
    }
    float mx = v[0];
#pragma unroll
    for (int s = 1; s < 8; ++s) mx = fmaxf(mx, v[s]);
    float m_new = fmaxf(m_run, mx);
    float f = expf(m_run - m_new);
    l_run *= f;
    acc *= f;
#pragma unroll
    for (int s = 0; s < 8; ++s) {
      float w = expf(v[s] - m_new);
      l_run += w;
      float4 e = *(const float4*)(enc_lds + s * 1024 + tid * 4);
      acc[0] += w * e.x; acc[1] += w * e.y; acc[2] += w * e.z; acc[3] += w * e.w;
    }
    m_run = m_new;
    __syncthreads();
  }

  *(f32x4*)(ctxp + ((size_t)(b * 16 + ch)) * 1024 + tid * 4) = acc;
  if (tid == 0) {
    ml[(b * 16 + ch) * 2]     = m_run;
    ml[(b * 16 + ch) * 2 + 1] = l_run;
  }
}

// ---------------- combine chunk partials -> context, emit bf16 into A[:,0:1024]
__global__ __launch_bounds__(256) void k_attn_combine(const float* __restrict__ ctxp,
    const float* __restrict__ ml, __bf16* __restrict__ A_bf) {
  int b = blockIdx.x;
  int tid = threadIdx.x;
  float M = -1e30f;
#pragma unroll
  for (int c = 0; c < 16; ++c) M = fmaxf(M, ml[(b * 16 + c) * 2]);
  float Z = 0.f;
  f32x4 num = {0.f, 0.f, 0.f, 0.f};
#pragma unroll
  for (int c = 0; c < 16; ++c) {
    float e = expf(ml[(b * 16 + c) * 2] - M);
    Z += e * ml[(b * 16 + c) * 2 + 1];
    f32x4 p = *(const f32x4*)(ctxp + ((size_t)(b * 16 + c)) * 1024 + tid * 4);
    num += e * p;
  }
  float inv = 1.f / Z;
  __bf16* dst = A_bf + b * NK2 + tid * 4;
#pragma unroll
  for (int i = 0; i < 4; ++i) dst[i] = (__bf16)(num[i] * inv);
}

// ---------------- out = A @ W_out^T + b_out via bf16 MFMA; 32 v-cols per wave
__global__ __launch_bounds__(256) void k_out_mfma(const __bf16* __restrict__ A,
    const float* __restrict__ Wout, const float* __restrict__ bout,
    float* __restrict__ out) {
  int lane = threadIdx.x & 63;
  int wave = threadIdx.x >> 6;
  int col  = lane & 15;
  int grp  = lane >> 4;
  int vb   = blockIdx.x * 128 + wave * 32;
  int va   = vb + col;
  int vc   = vb + 16 + col;
  int vaC  = va < NV ? va : NV - 1;
  int vcC  = vc < NV ? vc : NV - 1;

  const float*  wpA = Wout + (size_t)vaC * NK2 + grp * 8;
  const float*  wpB = Wout + (size_t)vcC * NK2 + grp * 8;
  const __bf16* ap  = A + grp * 8;   // row added per-fragment below (BUG FIX: col*NK2 was double-counted)

  f32x4 acc[4][2] = {};

#pragma unroll 2
  for (int ks = 0; ks < 64; ++ks) {
    int kb = ks * 32;
    float4 a0 = *(const float4*)(wpA + kb);
    float4 a1 = *(const float4*)(wpA + kb + 4);
    float4 c0 = *(const float4*)(wpB + kb);
    float4 c1 = *(const float4*)(wpB + kb + 4);
    bf16_8 bfA, bfB;
    bfA[0] = (__bf16)a0.x; bfA[1] = (__bf16)a0.y;
    bfA[2] = (__bf16)a0.z; bfA[3] = (__bf16)a0.w;
    bfA[4] = (__bf16)a1.x; bfA[5] = (__bf16)a1.y;
    bfA[6] = (__bf16)a1.z; bfA[7] = (__bf16)a1.w;
    bfB[0] = (__bf16)c0.x; bfB[1] = (__bf16)c0.y;
    bfB[2] = (__bf16)c0.z; bfB[3] = (__bf16)c0.w;
    bfB[4] = (__bf16)c1.x; bfB[5] = (__bf16)c1.y;
    bfB[6] = (__bf16)c1.z; bfB[7] = (__bf16)c1.w;
#pragma unroll
    for (int m = 0; m < 4; ++m) {
      bf16_8 a = *(const bf16_8*)(ap + (size_t)(m * 16 + col) * NK2 + kb);
      acc[m][0] = __builtin_amdgcn_mfma_f32_16x16x32_bf16(a, bfA, acc[m][0], 0, 0, 0);
      acc[m][1] = __builtin_amdgcn_mfma_f32_16x16x32_bf16(a, bfB, acc[m][1], 0, 0, 0);
    }
  }

#pragma unroll
  for (int n = 0; n < 2; ++n) {
    int vrow = vb + n * 16 + col;
    if (vrow < NV) {
      float bb = bout[vrow];
      int mrow = grp * 4;
#pragma unroll
      for (int m = 0; m < 4; ++m)
#pragma unroll
        for (int r = 0; r < 4; ++r)
          out[(size_t)(m * 16 + mrow + r) * NV + vrow] = acc[m][n][r] + bb;
    }
  }
}

extern "C" void kernel_launch(void* const* d_in, const int* in_sizes, int n_in,
                              void* d_out, int out_size, void* d_ws, size_t ws_size,
                              hipStream_t stream) {
  const int*   x      = (const int*)d_in[0];
  const float* h      = (const float*)d_in[1];
  const float* c      = (const float*)d_in[2];
  const float* enc    = (const float*)d_in[3];
  const int*   length = (const int*)d_in[4];
  const float* emb    = (const float*)d_in[5];
  const float* Wih    = (const float*)d_in[6];
  const float* bih    = (const float*)d_in[7];
  const float* Whh    = (const float*)d_in[8];
  const float* bhh    = (const float*)d_in[9];
  const float* Wb     = (const float*)d_in[10];
  const float* Wout   = (const float*)d_in[11];
  const float* bout   = (const float*)d_in[12];

  float* out = (float*)d_out;
  float* hn  = out + (size_t)NB * NV;          // h_new region of d_out
  // c_new region = hn + NB*NH (written by k_lstm)

  float* ws      = (float*)d_ws;
  float* gates   = ws;                              // NB*4H            (256K f32)
  float* t_ws    = gates + NB * 4 * NH;             // NB*NH            (64K f32)
  float* ctxp    = t_ws + NB * NH;                  // 16*NB*NH         (1M f32)
  float* ml      = ctxp + 16 * NB * NH;             // NB*16*2
  __bf16* A_bf   = (__bf16*)(ml + NB * 32);         // NB*NK2 bf16
  __bf16* Ag_bf  = A_bf + NB * NK2;                 // NB*NK2 bf16

  k_cvtAg<<<NB * NK2 / 256, 256, 0, stream>>>(x, h, emb, Ag_bf);
  k_gates_mfma<<<4096 / 16, 256, 0, stream>>>(Ag_bf, Wih, bih, Whh, bhh, gates);
  k_lstm<<<NB * NH / 256, 256, 0, stream>>>(gates, c, hn, A_bf);
  k_bilin<<<NB * 4, 256, 0, stream>>>(hn, Wb, t_ws);
  k_attn<<<NB * 16, 256, 0, stream>>>(t_ws, enc, length, ctxp, ml);
  k_attn_combine<<<NB, 256, 0, stream>>>(ctxp, ml, A_bf);
  k_out_mfma<<<(NV + 127) / 128, 256, 0, stream>>>(A_bf, Wout, bout, out);
}

// Round 6
// 308.130 us; speedup vs baseline: 1.1703x; 1.1703x over previous
//
#include <hip/hip_runtime.h>
#include <math.h>

constexpr int NB = 64;
constexpr int NS = 1024;
constexpr int NH = 1024;
constexpr int NE = 1024;
constexpr int NV = 50257;
constexpr int NK2 = 2048;

typedef __bf16 bf16_8 __attribute__((ext_vector_type(8)));
typedef float  f32x4  __attribute__((ext_vector_type(4)));

// ---------------- build A_g = [emb[x] | h] (64 x 2048) in bf16
__global__ __launch_bounds__(256) void k_cvtAg(const int* __restrict__ x,
    const float* __restrict__ h, const float* __restrict__ emb,
    __bf16* __restrict__ Ag) {
  int t = blockIdx.x * 256 + threadIdx.x;  // 0..131071
  int b = t >> 11, k = t & 2047;
  float v = (k < NE) ? emb[(size_t)x[b] * NE + k] : h[b * NH + (k - NE)];
  Ag[t] = (__bf16)v;
}

// ---------------- gates GEMM via bf16 MFMA (W streamed, no LDS staging)
__global__ __launch_bounds__(256) void k_gates_mfma(const __bf16* __restrict__ Ag,
    const float* __restrict__ Wih, const float* __restrict__ bih,
    const float* __restrict__ Whh, const float* __restrict__ bhh,
    float* __restrict__ gates) {
  __shared__ f32x4 red[4][4][64];
  int lane = threadIdx.x & 63;
  int wave = threadIdx.x >> 6;
  int col  = lane & 15;
  int grp  = lane >> 4;
  int j    = blockIdx.x * 16 + col;

  const float* Wsel = (wave < 2) ? Wih : Whh;
  const float*  wp  = Wsel + (size_t)j * 1024 + (wave & 1) * 512 + grp * 8;
  const __bf16* ap  = Ag + wave * 512 + grp * 8;

  f32x4 acc[4] = {};
#pragma unroll 4
  for (int ks = 0; ks < 16; ++ks) {
    int kb = ks * 32;
    float4 b0 = *(const float4*)(wp + kb);
    float4 b1 = *(const float4*)(wp + kb + 4);
    bf16_8 bf;
    bf[0] = (__bf16)b0.x; bf[1] = (__bf16)b0.y;
    bf[2] = (__bf16)b0.z; bf[3] = (__bf16)b0.w;
    bf[4] = (__bf16)b1.x; bf[5] = (__bf16)b1.y;
    bf[6] = (__bf16)b1.z; bf[7] = (__bf16)b1.w;
#pragma unroll
    for (int m = 0; m < 4; ++m) {
      bf16_8 a = *(const bf16_8*)(ap + (m * 16 + col) * NK2 + kb);
      acc[m] = __builtin_amdgcn_mfma_f32_16x16x32_bf16(a, bf, acc[m], 0, 0, 0);
    }
  }
#pragma unroll
  for (int m = 0; m < 4; ++m) red[wave][m][lane] = acc[m];
  __syncthreads();
  f32x4 s = red[0][wave][lane];
#pragma unroll
  for (int wv = 1; wv < 4; ++wv) s += red[wv][wave][lane];
  float bias = bih[j] + bhh[j];
  int b = wave * 16 + grp * 4;
#pragma unroll
  for (int r = 0; r < 4; ++r)
    gates[(b + r) * 4096 + j] = s[r] + bias;
}

// ---------------- LSTM cell elementwise (also emits bf16 h_new into A[:,1024:])
__global__ __launch_bounds__(256) void k_lstm(const float* __restrict__ gates,
    const float* __restrict__ c, float* __restrict__ hc_out,
    __bf16* __restrict__ A_bf) {
  int t = blockIdx.x * 256 + threadIdx.x;  // 0..NB*NH
  int b = t >> 10, hh = t & 1023;
  float ig = gates[b * 4096 + hh];
  float fg = gates[b * 4096 + 1024 + hh];
  float gg = gates[b * 4096 + 2048 + hh];
  float og = gates[b * 4096 + 3072 + hh];
  float i_ = 1.f / (1.f + expf(-ig));
  float f_ = 1.f / (1.f + expf(-fg));
  float g_ = tanhf(gg);
  float o_ = 1.f / (1.f + expf(-og));
  float cn = f_ * c[t] + i_ * g_;
  float hn = o_ * tanhf(cn);
  hc_out[t] = hn;                 // h_new
  hc_out[NB * NH + t] = cn;       // c_new
  A_bf[b * NK2 + 1024 + hh] = (__bf16)hn;
}

// ---------------- t = h_new @ W_bilin
__global__ __launch_bounds__(256) void k_bilin(const float* __restrict__ hnew,
    const float* __restrict__ Wb, float* __restrict__ t_out) {
  int b = blockIdx.x >> 2;
  int k = ((blockIdx.x & 3) << 8) + threadIdx.x;
  const float* hb = hnew + b * NH;
  float acc = 0.f;
#pragma unroll 8
  for (int hh = 0; hh < NH; ++hh)
    acc += hb[hh] * Wb[hh * NH + k];
  t_out[b * NH + k] = acc;
}

// ---------------- barrier-free flash attention: one WAVE per (b, 16-row strip).
// Per row: enc row in regs (4x float4/lane), dot vs reg-resident t, butterfly
// reduce so ALL lanes hold energy, then reuse the same regs for the weighted
// context accumulate. No LDS, no syncthreads -> loads issue continuously.
// Masked rows (s>=len) get value 0 (not -inf) and DO accumulate, per reference.
__global__ __launch_bounds__(256) void k_attn(const float* __restrict__ t_in,
    const float* __restrict__ enc, const int* __restrict__ length,
    float* __restrict__ ctxp, float* __restrict__ ml) {
  int b     = blockIdx.x >> 4;                                   // 64
  int strip = ((blockIdx.x & 15) << 2) + (threadIdx.x >> 6);     // 0..63
  int lane  = threadIdx.x & 63;
  int len   = length[b];
  int s0    = strip * 16;

  const float4* tp4 = (const float4*)(t_in + b * NH);
  float4 tv[4];
#pragma unroll
  for (int i = 0; i < 4; ++i) tv[i] = tp4[i * 64 + lane];

  const float4* ep4 = (const float4*)(enc + ((size_t)b * NS + s0) * NH);

  float m_run = -1e30f, l_run = 0.f;
  f32x4 acc[4] = {};

#pragma unroll 2
  for (int r = 0; r < 16; ++r) {
    float4 e[4];
#pragma unroll
    for (int i = 0; i < 4; ++i) e[i] = ep4[r * 256 + i * 64 + lane];
    float d = 0.f;
#pragma unroll
    for (int i = 0; i < 4; ++i)
      d += tv[i].x * e[i].x + tv[i].y * e[i].y + tv[i].z * e[i].z + tv[i].w * e[i].w;
#pragma unroll
    for (int off = 32; off; off >>= 1) d += __shfl_xor(d, off);
    float v = (s0 + r < len) ? d : 0.f;
    float m_new = fmaxf(m_run, v);
    float f = expf(m_run - m_new);     // first iter: expf(-inf)=0, clean
    float w = expf(v - m_new);
    l_run = l_run * f + w;
#pragma unroll
    for (int i = 0; i < 4; ++i) {
      acc[i][0] = acc[i][0] * f + w * e[i].x;
      acc[i][1] = acc[i][1] * f + w * e[i].y;
      acc[i][2] = acc[i][2] * f + w * e[i].z;
      acc[i][3] = acc[i][3] * f + w * e[i].w;
    }
    m_run = m_new;
  }

  int idx = b * 64 + strip;
  float* P = ctxp + (size_t)idx * 1024;
#pragma unroll
  for (int i = 0; i < 4; ++i)
    *(f32x4*)(P + (i * 64 + lane) * 4) = acc[i];
  if (lane == 0) {
    ml[idx * 2]     = m_run;
    ml[idx * 2 + 1] = l_run;
  }
}

// ---------------- combine 64 strip partials -> context, emit bf16 into A[:,0:1024]
__global__ __launch_bounds__(256) void k_attn_combine(const float* __restrict__ ctxp,
    const float* __restrict__ ml, __bf16* __restrict__ A_bf) {
  int b = blockIdx.x;
  int tid = threadIdx.x;
  float M = -1e30f;
#pragma unroll
  for (int c = 0; c < 64; ++c) M = fmaxf(M, ml[(b * 64 + c) * 2]);
  float Z = 0.f;
  f32x4 num = {0.f, 0.f, 0.f, 0.f};
#pragma unroll 4
  for (int c = 0; c < 64; ++c) {
    float e = expf(ml[(b * 64 + c) * 2] - M);
    Z += e * ml[(b * 64 + c) * 2 + 1];
    f32x4 p = *(const f32x4*)(ctxp + ((size_t)(b * 64 + c)) * 1024 + tid * 4);
    num += e * p;
  }
  float inv = 1.f / Z;
  __bf16* dst = A_bf + b * NK2 + tid * 4;
#pragma unroll
  for (int i = 0; i < 4; ++i) dst[i] = (__bf16)(num[i] * inv);
}

// ---------------- out = A @ W_out^T + b_out via bf16 MFMA; one wave per block,
// 32 v-cols per wave (grid 1571 -> ~6.1 waves/CU, small tail imbalance)
__global__ __launch_bounds__(64) void k_out_mfma(const __bf16* __restrict__ A,
    const float* __restrict__ Wout, const float* __restrict__ bout,
    float* __restrict__ out) {
  int lane = threadIdx.x;
  int col  = lane & 15;
  int grp  = lane >> 4;
  int vb   = blockIdx.x * 32;
  int va   = vb + col;
  int vc   = vb + 16 + col;
  int vaC  = va < NV ? va : NV - 1;
  int vcC  = vc < NV ? vc : NV - 1;

  const float*  wpA = Wout + (size_t)vaC * NK2 + grp * 8;
  const float*  wpB = Wout + (size_t)vcC * NK2 + grp * 8;
  const __bf16* ap  = A + grp * 8;

  f32x4 acc[4][2] = {};

#pragma unroll 2
  for (int ks = 0; ks < 64; ++ks) {
    int kb = ks * 32;
    float4 a0 = *(const float4*)(wpA + kb);
    float4 a1 = *(const float4*)(wpA + kb + 4);
    float4 c0 = *(const float4*)(wpB + kb);
    float4 c1 = *(const float4*)(wpB + kb + 4);
    bf16_8 bfA, bfB;
    bfA[0] = (__bf16)a0.x; bfA[1] = (__bf16)a0.y;
    bfA[2] = (__bf16)a0.z; bfA[3] = (__bf16)a0.w;
    bfA[4] = (__bf16)a1.x; bfA[5] = (__bf16)a1.y;
    bfA[6] = (__bf16)a1.z; bfA[7] = (__bf16)a1.w;
    bfB[0] = (__bf16)c0.x; bfB[1] = (__bf16)c0.y;
    bfB[2] = (__bf16)c0.z; bfB[3] = (__bf16)c0.w;
    bfB[4] = (__bf16)c1.x; bfB[5] = (__bf16)c1.y;
    bfB[6] = (__bf16)c1.z; bfB[7] = (__bf16)c1.w;
#pragma unroll
    for (int m = 0; m < 4; ++m) {
      bf16_8 a = *(const bf16_8*)(ap + (size_t)(m * 16 + col) * NK2 + kb);
      acc[m][0] = __builtin_amdgcn_mfma_f32_16x16x32_bf16(a, bfA, acc[m][0], 0, 0, 0);
      acc[m][1] = __builtin_amdgcn_mfma_f32_16x16x32_bf16(a, bfB, acc[m][1], 0, 0, 0);
    }
  }

#pragma unroll
  for (int n = 0; n < 2; ++n) {
    int vrow = vb + n * 16 + col;
    if (vrow < NV) {
      float bb = bout[vrow];
      int mrow = grp * 4;
#pragma unroll
      for (int m = 0; m < 4; ++m)
#pragma unroll
        for (int r = 0; r < 4; ++r)
          out[(size_t)(m * 16 + mrow + r) * NV + vrow] = acc[m][n][r] + bb;
    }
  }
}

extern "C" void kernel_launch(void* const* d_in, const int* in_sizes, int n_in,
                              void* d_out, int out_size, void* d_ws, size_t ws_size,
                              hipStream_t stream) {
  const int*   x      = (const int*)d_in[0];
  const float* h      = (const float*)d_in[1];
  const float* c      = (const float*)d_in[2];
  const float* enc    = (const float*)d_in[3];
  const int*   length = (const int*)d_in[4];
  const float* emb    = (const float*)d_in[5];
  const float* Wih    = (const float*)d_in[6];
  const float* bih    = (const float*)d_in[7];
  const float* Whh    = (const float*)d_in[8];
  const float* bhh    = (const float*)d_in[9];
  const float* Wb     = (const float*)d_in[10];
  const float* Wout   = (const float*)d_in[11];
  const float* bout   = (const float*)d_in[12];

  float* out = (float*)d_out;
  float* hn  = out + (size_t)NB * NV;          // h_new region of d_out
  // c_new region = hn + NB*NH (written by k_lstm)

  float* ws      = (float*)d_ws;
  float* gates   = ws;                              // NB*4H f32
  float* t_ws    = gates + NB * 4 * NH;             // NB*NH f32
  float* ctxp    = t_ws + NB * NH;                  // 64*NB*NH f32 (16MB)
  float* ml      = ctxp + 64 * (size_t)NB * 1024;   // NB*64*2 f32
  __bf16* A_bf   = (__bf16*)(ml + NB * 128);        // NB*NK2 bf16
  __bf16* Ag_bf  = A_bf + NB * NK2;                 // NB*NK2 bf16

  k_cvtAg<<<NB * NK2 / 256, 256, 0, stream>>>(x, h, emb, Ag_bf);
  k_gates_mfma<<<4096 / 16, 256, 0, stream>>>(Ag_bf, Wih, bih, Whh, bhh, gates);
  k_lstm<<<NB * NH / 256, 256, 0, stream>>>(gates, c, hn, A_bf);
  k_bilin<<<NB * 4, 256, 0, stream>>>(hn, Wb, t_ws);
  k_attn<<<NB * 16, 256, 0, stream>>>(t_ws, enc, length, ctxp, ml);
  k_attn_combine<<<NB, 256, 0, stream>>>(ctxp, ml, A_bf);
  k_out_mfma<<<(NV + 31) / 32, 64, 0, stream>>>(A_bf, Wout, bout, out);
}